// Round 1
// baseline (454.453 us; speedup 1.0000x reference)
//
#include <hip/hip_runtime.h>
#include <stdint.h>

#define SEQLEN 4096
#define DMODEL 1024
#define NHEADS 16
#define DKDIM  64

typedef unsigned short u16;
typedef unsigned int   u32;
using f32x4 = __attribute__((ext_vector_type(4))) float;
using i32x4 = __attribute__((ext_vector_type(4))) int;

__device__ __forceinline__ float bf2f(u16 u) {
    u32 x = ((u32)u) << 16;
    return __builtin_bit_cast(float, x);
}
__device__ __forceinline__ u16 f2bf(float f) {
    u32 x = __builtin_bit_cast(u32, f);
    u32 r = x + 0x7fffu + ((x >> 16) & 1u);   // RNE
    return (u16)(r >> 16);
}

// D = A*B + C, 16x16x32 bf16. Inline asm avoids builtin vector-type signature risk.
// A: lane holds A[lane&15][(lane>>4)*8 + j]; B: lane holds B[(lane>>4)*8 + j][lane&15];
// C/D: lane holds D[(lane>>4)*4 + r][lane&15]   (verified layouts, m89/m91)
__device__ __forceinline__ void mfma_bf16(f32x4& d, i32x4 a, i32x4 b) {
    asm("v_mfma_f32_16x16x32_bf16 %0, %1, %2, %0" : "+v"(d) : "v"(a), "v"(b));
}

// ---------------- LayerNorm: h fp32 [4096][1024] -> hn bf16 ----------------
__global__ __launch_bounds__(256) void ln_kernel(const float* __restrict__ h,
                                                 const float* __restrict__ gamma,
                                                 const float* __restrict__ beta,
                                                 u16* __restrict__ hn) {
    int row = blockIdx.x;
    int t = threadIdx.x;
    float4 v = reinterpret_cast<const float4*>(h + (size_t)row * DMODEL)[t];
    float s  = v.x + v.y + v.z + v.w;
    float s2 = v.x*v.x + v.y*v.y + v.z*v.z + v.w*v.w;
#pragma unroll
    for (int off = 1; off < 64; off <<= 1) {
        s  += __shfl_xor(s, off);
        s2 += __shfl_xor(s2, off);
    }
    __shared__ float red[8];
    int wid = t >> 6, lane = t & 63;
    if (lane == 0) { red[wid] = s; red[4 + wid] = s2; }
    __syncthreads();
    s  = red[0] + red[1] + red[2] + red[3];
    s2 = red[4] + red[5] + red[6] + red[7];
    float mu   = s * (1.0f / DMODEL);
    float rstd = rsqrtf(s2 * (1.0f / DMODEL) - mu * mu + 1e-5f);
    float4 g = reinterpret_cast<const float4*>(gamma)[t];
    float4 b = reinterpret_cast<const float4*>(beta)[t];
    ushort4 o;
    o.x = f2bf((v.x - mu) * rstd * g.x + b.x);
    o.y = f2bf((v.y - mu) * rstd * g.y + b.y);
    o.z = f2bf((v.z - mu) * rstd * g.z + b.z);
    o.w = f2bf((v.w - mu) * rstd * g.w + b.w);
    reinterpret_cast<ushort4*>(hn + (size_t)row * DMODEL)[t] = o;
}

// ------------- Weight transpose+convert: W fp32 [K][N] -> Wt bf16 [N][K] -------------
__global__ __launch_bounds__(256) void wconv_kernel(const float* __restrict__ W,
                                                    u16* __restrict__ Wt) {
    __shared__ float tile[32][33];
    int bx = blockIdx.x * 32;   // n
    int by = blockIdx.y * 32;   // k (input dim)
    int tx = threadIdx.x & 31, ty = threadIdx.x >> 5;  // 32x8
#pragma unroll
    for (int i = 0; i < 32; i += 8)
        tile[ty + i][tx] = W[(size_t)(by + ty + i) * DMODEL + bx + tx];
    __syncthreads();
#pragma unroll
    for (int i = 0; i < 32; i += 8)
        Wt[(size_t)(bx + ty + i) * DMODEL + by + tx] = f2bf(tile[tx][ty + i]);
}

// ---------------- RoPE cos/sin tables: [4096][32] fp32 each ----------------
__global__ void rope_table_kernel(float* __restrict__ cosT, float* __restrict__ sinT) {
    int idx = blockIdx.x * 256 + threadIdx.x;
    int s = idx >> 5, i = idx & 31;
    float theta = powf(10000.0f, -2.0f * (float)i / 64.0f);
    float ang = (float)s * theta;
    cosT[idx] = cosf(ang);
    sinT[idx] = sinf(ang);
}

// ---------------- GEMM: C[M=4096][N=1024] = A bf16 [M][1024] @ Bt^T ----------------
// Bt is [N][K] row-major (pre-transposed weight). EPI=0: +bias, write bf16 to
// head-major [head][seq][64]. EPI=1: +bias +residual, write fp32 row-major.
template <int EPI>
__global__ __launch_bounds__(256) void gemm_kernel(const u16* __restrict__ A,
                                                   const u16* __restrict__ Bt,
                                                   const float* __restrict__ bias,
                                                   const float* __restrict__ resid,
                                                   void* __restrict__ outp) {
    constexpr int Kdim = DMODEL;
    __shared__ alignas(16) u16 As[128][40];
    __shared__ alignas(16) u16 Bs[128][40];
    int bm = blockIdx.x, bn = blockIdx.y;
    int tid = threadIdx.x;
    int wid = tid >> 6, lane = tid & 63;
    int wm = wid >> 1, wn = wid & 1;          // 2x2 waves, each 64x64 output
    int lrow = lane & 15, lgrp = lane >> 4;
    f32x4 acc[4][4] = {};
    for (int k0 = 0; k0 < Kdim; k0 += 32) {
#pragma unroll
        for (int rep = 0; rep < 2; rep++) {
            int t = tid + rep * 256;
            int r = t >> 2, c = (t & 3) * 8;
            *reinterpret_cast<i32x4*>(&As[r][c]) =
                *reinterpret_cast<const i32x4*>(A + (size_t)(bm * 128 + r) * Kdim + k0 + c);
            *reinterpret_cast<i32x4*>(&Bs[r][c]) =
                *reinterpret_cast<const i32x4*>(Bt + (size_t)(bn * 128 + r) * Kdim + k0 + c);
        }
        __syncthreads();
        i32x4 af[4], bfr[4];
#pragma unroll
        for (int mi = 0; mi < 4; mi++)
            af[mi] = *reinterpret_cast<i32x4*>(&As[wm * 64 + mi * 16 + lrow][lgrp * 8]);
#pragma unroll
        for (int ni = 0; ni < 4; ni++)
            bfr[ni] = *reinterpret_cast<i32x4*>(&Bs[wn * 64 + ni * 16 + lrow][lgrp * 8]);
#pragma unroll
        for (int mi = 0; mi < 4; mi++)
#pragma unroll
            for (int ni = 0; ni < 4; ni++)
                mfma_bf16(acc[mi][ni], af[mi], bfr[ni]);
        __syncthreads();
    }
#pragma unroll
    for (int mi = 0; mi < 4; mi++) {
#pragma unroll
        for (int ni = 0; ni < 4; ni++) {
            int n = bn * 128 + wn * 64 + ni * 16 + lrow;
            float bv = bias[n];
#pragma unroll
            for (int r = 0; r < 4; r++) {
                int m = bm * 128 + wm * 64 + mi * 16 + lgrp * 4 + r;
                float val = acc[mi][ni][r] + bv;
                if (EPI == 0) {
                    u16* o = (u16*)outp;
                    int head = n >> 6, dv = n & 63;
                    o[(size_t)(head * SEQLEN + m) * DKDIM + dv] = f2bf(val);
                } else {
                    float* o = (float*)outp;
                    o[(size_t)m * DMODEL + n] = val + resid[(size_t)m * DMODEL + n];
                }
            }
        }
    }
}

// ---------------- RoPE in-place on q and k, layout [head][seq][64] bf16 ----------------
__global__ __launch_bounds__(256) void rope_kernel(u16* __restrict__ q, u16* __restrict__ k,
                                                   const float* __restrict__ cosT,
                                                   const float* __restrict__ sinT) {
    int rid = blockIdx.x * 4 + (threadIdx.x >> 6);
    int lane = threadIdx.x & 63;
    u16* base = q;
    int r = rid;
    if (rid >= NHEADS * SEQLEN) { base = k; r = rid - NHEADS * SEQLEN; }
    int s = r & (SEQLEN - 1);
    u16* p = base + (size_t)r * DKDIM;
    float x  = bf2f(p[lane]);
    float xp = __shfl_xor(x, 32);
    int fi = lane & 31;
    float c  = cosT[s * 32 + fi];
    float sn = sinT[s * 32 + fi];
    float nh = (lane < 32) ? -xp : xp;
    p[lane] = f2bf(x * c + nh * sn);
}

// ---------------- Flash attention, causal. q/k/v bf16 [head][seq][64] ----------------
// Block: 4 waves, Q-tile 64 rows (16/wave), K-tile 64. Output bf16 [seq][1024].
__global__ __launch_bounds__(256) void attn_kernel(const u16* __restrict__ q,
                                                   const u16* __restrict__ k,
                                                   const u16* __restrict__ v,
                                                   u16* __restrict__ o) {
    __shared__ alignas(16) u16 Kl[64][72];
    __shared__ alignas(16) u16 Vt[64][72];        // V transposed: Vt[dv][krow]
    __shared__ alignas(16) u16 Pl[4][16][72];     // per-wave P staging
    int h = blockIdx.y, qt = blockIdx.x;
    int q0 = qt * 64;
    int tid = threadIdx.x, wid = tid >> 6, lane = tid & 63;
    int lrow = lane & 15, lgrp = lane >> 4;
    const u16* Qh = q + (size_t)h * SEQLEN * DKDIM;
    const u16* Kh = k + (size_t)h * SEQLEN * DKDIM;
    const u16* Vh = v + (size_t)h * SEQLEN * DKDIM;
    i32x4 qf0, qf1;
    {
        const u16* qp = Qh + (size_t)(q0 + wid * 16 + lrow) * DKDIM + lgrp * 8;
        qf0 = *reinterpret_cast<const i32x4*>(qp);
        qf1 = *reinterpret_cast<const i32x4*>(qp + 32);
    }
    f32x4 oacc[4] = {};
    float m_run[4] = {-1e30f, -1e30f, -1e30f, -1e30f};
    float l_run[4] = {};
    for (int kt = 0; kt <= qt; kt++) {
        int k0 = kt * 64;
#pragma unroll
        for (int rep = 0; rep < 2; rep++) {
            int t = tid + rep * 256;
            int r = t >> 3, c = (t & 7) * 8;
            i32x4 kd = *reinterpret_cast<const i32x4*>(Kh + (size_t)(k0 + r) * DKDIM + c);
            *reinterpret_cast<i32x4*>(&Kl[r][c]) = kd;
            i32x4 vd = *reinterpret_cast<const i32x4*>(Vh + (size_t)(k0 + r) * DKDIM + c);
            union { i32x4 vv; u16 us[8]; } un;
            un.vv = vd;
#pragma unroll
            for (int j = 0; j < 8; j++) Vt[c + j][r] = un.us[j];
        }
        __syncthreads();
        f32x4 sacc[4] = {};
#pragma unroll
        for (int kb = 0; kb < 4; kb++) {
            i32x4 kf0 = *reinterpret_cast<i32x4*>(&Kl[kb * 16 + lrow][lgrp * 8]);
            i32x4 kf1 = *reinterpret_cast<i32x4*>(&Kl[kb * 16 + lrow][32 + lgrp * 8]);
            mfma_bf16(sacc[kb], qf0, kf0);
            mfma_bf16(sacc[kb], qf1, kf1);
        }
#pragma unroll
        for (int r = 0; r < 4; r++) {
            int grow = q0 + wid * 16 + lgrp * 4 + r;
            float mx = -1e30f;
#pragma unroll
            for (int kb = 0; kb < 4; kb++) {
                int gcol = k0 + kb * 16 + lrow;
                float sv = sacc[kb][r] * 0.125f;           // 1/sqrt(64)
                sv = (gcol <= grow) ? sv : -1e30f;          // causal mask
                sacc[kb][r] = sv;
                mx = fmaxf(mx, sv);
            }
#pragma unroll
            for (int off = 1; off < 16; off <<= 1) mx = fmaxf(mx, __shfl_xor(mx, off));
            float mnew = fmaxf(m_run[r], mx);
            float fold = __expf(m_run[r] - mnew);
            float psum = 0.f;
#pragma unroll
            for (int kb = 0; kb < 4; kb++) {
                float p = __expf(sacc[kb][r] - mnew);
                sacc[kb][r] = p;
                psum += p;
            }
#pragma unroll
            for (int off = 1; off < 16; off <<= 1) psum += __shfl_xor(psum, off);
            l_run[r] = l_run[r] * fold + psum;
            m_run[r] = mnew;
#pragma unroll
            for (int nb = 0; nb < 4; nb++) oacc[nb][r] *= fold;
#pragma unroll
            for (int kb = 0; kb < 4; kb++)
                Pl[wid][lgrp * 4 + r][kb * 16 + lrow] = f2bf(sacc[kb][r]);
        }
        __syncthreads();
        i32x4 pf0 = *reinterpret_cast<i32x4*>(&Pl[wid][lrow][lgrp * 8]);
        i32x4 pf1 = *reinterpret_cast<i32x4*>(&Pl[wid][lrow][32 + lgrp * 8]);
#pragma unroll
        for (int nb = 0; nb < 4; nb++) {
            i32x4 vf0 = *reinterpret_cast<i32x4*>(&Vt[nb * 16 + lrow][lgrp * 8]);
            i32x4 vf1 = *reinterpret_cast<i32x4*>(&Vt[nb * 16 + lrow][32 + lgrp * 8]);
            mfma_bf16(oacc[nb], pf0, vf0);
            mfma_bf16(oacc[nb], pf1, vf1);
        }
        __syncthreads();
    }
#pragma unroll
    for (int nb = 0; nb < 4; nb++) {
#pragma unroll
        for (int r = 0; r < 4; r++) {
            int srow = q0 + wid * 16 + lgrp * 4 + r;
            int col = h * DKDIM + nb * 16 + lrow;
            o[(size_t)srow * DMODEL + col] = f2bf(oacc[nb][r] / l_run[r]);
        }
    }
}

extern "C" void kernel_launch(void* const* d_in, const int* in_sizes, int n_in,
                              void* d_out, int out_size, void* d_ws, size_t ws_size,
                              hipStream_t stream) {
    const float* h     = (const float*)d_in[0];
    const float* gamma = (const float*)d_in[1];
    const float* beta  = (const float*)d_in[2];
    const float* Wq    = (const float*)d_in[3];
    const float* bq    = (const float*)d_in[4];
    const float* Wk    = (const float*)d_in[5];
    const float* bk    = (const float*)d_in[6];
    const float* Wv    = (const float*)d_in[7];
    const float* bv    = (const float*)d_in[8];
    const float* Wo    = (const float*)d_in[9];
    const float* bo    = (const float*)d_in[10];
    float* out = (float*)d_out;

    char* ws = (char*)d_ws;
    u16* hn   = (u16*)(ws);                        // 8 MiB; reused as attn output
    u16* wqT  = (u16*)(ws + (8ull  << 20));
    u16* wkT  = (u16*)(ws + (10ull << 20));
    u16* wvT  = (u16*)(ws + (12ull << 20));
    u16* woT  = (u16*)(ws + (14ull << 20));
    u16* qb   = (u16*)(ws + (16ull << 20));        // [16][4096][64] bf16
    u16* kb_  = (u16*)(ws + (24ull << 20));
    u16* vb   = (u16*)(ws + (32ull << 20));
    float* cosT = (float*)(ws + (40ull << 20));
    float* sinT = (float*)(ws + (40ull << 20) + (512ull << 10));
    u16* attn = hn;                                // alias: hn dead after QKV GEMMs

    ln_kernel<<<SEQLEN, 256, 0, stream>>>(h, gamma, beta, hn);
    dim3 wgrid(32, 32);
    wconv_kernel<<<wgrid, 256, 0, stream>>>(Wq, wqT);
    wconv_kernel<<<wgrid, 256, 0, stream>>>(Wk, wkT);
    wconv_kernel<<<wgrid, 256, 0, stream>>>(Wv, wvT);
    wconv_kernel<<<wgrid, 256, 0, stream>>>(Wo, woT);
    rope_table_kernel<<<(SEQLEN * 32) / 256, 256, 0, stream>>>(cosT, sinT);
    dim3 ggrid(32, 8);
    gemm_kernel<0><<<ggrid, 256, 0, stream>>>(hn, wqT, bq, nullptr, qb);
    gemm_kernel<0><<<ggrid, 256, 0, stream>>>(hn, wkT, bk, nullptr, kb_);
    gemm_kernel<0><<<ggrid, 256, 0, stream>>>(hn, wvT, bv, nullptr, vb);
    rope_kernel<<<(2 * NHEADS * SEQLEN) / 4, 256, 0, stream>>>(qb, kb_, cosT, sinT);
    dim3 agrid(SEQLEN / 64, NHEADS);
    attn_kernel<<<agrid, 256, 0, stream>>>(qb, kb_, vb, attn);
    gemm_kernel<1><<<ggrid, 256, 0, stream>>>(attn, woT, bo, h, out);
}

// Round 2
// 275.057 us; speedup vs baseline: 1.6522x; 1.6522x over previous
//
#include <hip/hip_runtime.h>
#include <stdint.h>

#define SEQLEN 4096
#define DMODEL 1024
#define NHEADS 16
#define DKDIM  64

typedef unsigned short u16;
typedef unsigned int   u32;
using f32x4 = __attribute__((ext_vector_type(4))) float;
using i32x4 = __attribute__((ext_vector_type(4))) int;
using i32x2 = __attribute__((ext_vector_type(2))) int;

__device__ __forceinline__ float bf2f(u16 u) {
    u32 x = ((u32)u) << 16;
    return __builtin_bit_cast(float, x);
}
__device__ __forceinline__ u16 f2bf(float f) {
    u32 x = __builtin_bit_cast(u32, f);
    u32 r = x + 0x7fffu + ((x >> 16) & 1u);   // RNE
    return (u16)(r >> 16);
}

// 16x16x32: A lane holds A[lane&15][(lane>>4)*8+j]; B: B[(lane>>4)*8+j][lane&15];
// C/D: D[(lane>>4)*4+r][lane&15]
__device__ __forceinline__ void mfma_bf16(f32x4& d, i32x4 a, i32x4 b) {
    asm("v_mfma_f32_16x16x32_bf16 %0, %1, %2, %0" : "+v"(d) : "v"(a), "v"(b));
}
// 16x16x16: A lane holds A[lane&15][(lane>>4)*4+j]; B: B[(lane>>4)*4+j][lane&15]
__device__ __forceinline__ void mfma16_bf16(f32x4& d, i32x2 a, i32x2 b) {
    asm("v_mfma_f32_16x16x16_bf16 %0, %1, %2, %0" : "+v"(d) : "v"(a), "v"(b));
}

// async global->LDS, 16B per lane; LDS dest = wave-uniform base + lane*16
#define ASYNC_COPY16(gsrc, ldst) \
    __builtin_amdgcn_global_load_lds((const __attribute__((address_space(1))) void*)(gsrc), \
                                     (__attribute__((address_space(3))) void*)(ldst), 16, 0, 0)

// ---------------- LayerNorm: h fp32 [4096][1024] -> hn bf16 ----------------
__global__ __launch_bounds__(256) void ln_kernel(const float* __restrict__ h,
                                                 const float* __restrict__ gamma,
                                                 const float* __restrict__ beta,
                                                 u16* __restrict__ hn) {
    int row = blockIdx.x;
    int t = threadIdx.x;
    float4 v = reinterpret_cast<const float4*>(h + (size_t)row * DMODEL)[t];
    float s  = v.x + v.y + v.z + v.w;
    float s2 = v.x*v.x + v.y*v.y + v.z*v.z + v.w*v.w;
#pragma unroll
    for (int off = 1; off < 64; off <<= 1) {
        s  += __shfl_xor(s, off);
        s2 += __shfl_xor(s2, off);
    }
    __shared__ float red[8];
    int wid = t >> 6, lane = t & 63;
    if (lane == 0) { red[wid] = s; red[4 + wid] = s2; }
    __syncthreads();
    s  = red[0] + red[1] + red[2] + red[3];
    s2 = red[4] + red[5] + red[6] + red[7];
    float mu   = s * (1.0f / DMODEL);
    float rstd = rsqrtf(s2 * (1.0f / DMODEL) - mu * mu + 1e-5f);
    float4 g = reinterpret_cast<const float4*>(gamma)[t];
    float4 b = reinterpret_cast<const float4*>(beta)[t];
    ushort4 o;
    o.x = f2bf((v.x - mu) * rstd * g.x + b.x);
    o.y = f2bf((v.y - mu) * rstd * g.y + b.y);
    o.z = f2bf((v.z - mu) * rstd * g.z + b.z);
    o.w = f2bf((v.w - mu) * rstd * g.w + b.w);
    reinterpret_cast<ushort4*>(hn + (size_t)row * DMODEL)[t] = o;
}

// ------------- Weight transpose+convert: W fp32 [K][N] -> Wt bf16 [N][K] -------------
__global__ __launch_bounds__(256) void wconv_kernel(const float* __restrict__ W,
                                                    u16* __restrict__ Wt) {
    __shared__ float tile[32][33];
    int bx = blockIdx.x * 32;   // n
    int by = blockIdx.y * 32;   // k
    int tx = threadIdx.x & 31, ty = threadIdx.x >> 5;
#pragma unroll
    for (int i = 0; i < 32; i += 8)
        tile[ty + i][tx] = W[(size_t)(by + ty + i) * DMODEL + bx + tx];
    __syncthreads();
#pragma unroll
    for (int i = 0; i < 32; i += 8)
        Wt[(size_t)(bx + ty + i) * DMODEL + by + tx] = f2bf(tile[tx][ty + i]);
}

// ---------------- RoPE cos/sin tables: [4096][32] fp32 each ----------------
__global__ void rope_table_kernel(float* __restrict__ cosT, float* __restrict__ sinT) {
    int idx = blockIdx.x * 256 + threadIdx.x;
    int s = idx >> 5, i = idx & 31;
    float theta = powf(10000.0f, -2.0f * (float)i / 64.0f);
    float ang = (float)s * theta;
    cosT[idx] = cosf(ang);
    sinT[idx] = sinf(ang);
}

// ---------------- GEMM: C[4096][1024] = A bf16 [4096][1024] @ Bt^T ----------------
// EPI=0: +bias, RoPE, write bf16 [head][seq][64] (Q,K).
// EPI=1: +bias +residual, write fp32 [seq][1024] (final).
// EPI=2: +bias, write bf16 V^T [head][64][seq] (V).
template <int EPI>
__global__ __launch_bounds__(256) void gemm_kernel(const u16* __restrict__ A,
                                                   const u16* __restrict__ Bt,
                                                   const float* __restrict__ bias,
                                                   const float* __restrict__ resid,
                                                   const float* __restrict__ cosT,
                                                   const float* __restrict__ sinT,
                                                   void* __restrict__ outp) {
    constexpr int Kdim = DMODEL;
    __shared__ alignas(16) u16 As[128][40];
    __shared__ alignas(16) u16 Bs[128][40];
    int bm = blockIdx.x, bn = blockIdx.y;
    int tid = threadIdx.x;
    int wid = tid >> 6, lane = tid & 63;
    int wm = wid >> 1, wn = wid & 1;
    int lrow = lane & 15, lgrp = lane >> 4;
    f32x4 acc[4][4] = {};
    for (int k0 = 0; k0 < Kdim; k0 += 32) {
#pragma unroll
        for (int rep = 0; rep < 2; rep++) {
            int t = tid + rep * 256;
            int r = t >> 2, c = (t & 3) * 8;
            *reinterpret_cast<i32x4*>(&As[r][c]) =
                *reinterpret_cast<const i32x4*>(A + (size_t)(bm * 128 + r) * Kdim + k0 + c);
            *reinterpret_cast<i32x4*>(&Bs[r][c]) =
                *reinterpret_cast<const i32x4*>(Bt + (size_t)(bn * 128 + r) * Kdim + k0 + c);
        }
        __syncthreads();
        i32x4 af[4], bfr[4];
#pragma unroll
        for (int mi = 0; mi < 4; mi++)
            af[mi] = *reinterpret_cast<i32x4*>(&As[wm * 64 + mi * 16 + lrow][lgrp * 8]);
#pragma unroll
        for (int ni = 0; ni < 4; ni++)
            bfr[ni] = *reinterpret_cast<i32x4*>(&Bs[wn * 64 + ni * 16 + lrow][lgrp * 8]);
#pragma unroll
        for (int mi = 0; mi < 4; mi++)
#pragma unroll
            for (int ni = 0; ni < 4; ni++)
                mfma_bf16(acc[mi][ni], af[mi], bfr[ni]);
        __syncthreads();
    }
    if (EPI == 0) {
        u16* o = (u16*)outp;
#pragma unroll
        for (int mi = 0; mi < 4; mi++) {
#pragma unroll
            for (int nl = 0; nl < 2; nl++) {
                int nA = bn * 128 + wn * 64 + nl * 16 + lrow;   // d&63 < 32
                int nB = nA + 32;
                int head = nA >> 6;
                int dA = nA & 63, dB = dA + 32;
                int fi = nl * 16 + lrow;                        // d & 31
                float bvA = bias[nA], bvB = bias[nB];
#pragma unroll
                for (int r = 0; r < 4; r++) {
                    int m = bm * 128 + wm * 64 + mi * 16 + lgrp * 4 + r;
                    float c  = cosT[m * 32 + fi];
                    float sn = sinT[m * 32 + fi];
                    float xA = acc[mi][nl][r] + bvA;
                    float xB = acc[mi][nl + 2][r] + bvB;
                    o[(size_t)(head * SEQLEN + m) * DKDIM + dA] = f2bf(xA * c - xB * sn);
                    o[(size_t)(head * SEQLEN + m) * DKDIM + dB] = f2bf(xB * c + xA * sn);
                }
            }
        }
    } else if (EPI == 2) {
        u16* o = (u16*)outp;
#pragma unroll
        for (int mi = 0; mi < 4; mi++) {
#pragma unroll
            for (int ni = 0; ni < 4; ni++) {
                int n = bn * 128 + wn * 64 + ni * 16 + lrow;
                int head = n >> 6, dv = n & 63;
                float bv = bias[n];
                int m = bm * 128 + wm * 64 + mi * 16 + lgrp * 4;
                ushort4 w4;
                w4.x = f2bf(acc[mi][ni][0] + bv);
                w4.y = f2bf(acc[mi][ni][1] + bv);
                w4.z = f2bf(acc[mi][ni][2] + bv);
                w4.w = f2bf(acc[mi][ni][3] + bv);
                *reinterpret_cast<ushort4*>(&o[(size_t)(head * DKDIM + dv) * SEQLEN + m]) = w4;
            }
        }
    } else {
#pragma unroll
        for (int mi = 0; mi < 4; mi++) {
#pragma unroll
            for (int ni = 0; ni < 4; ni++) {
                int n = bn * 128 + wn * 64 + ni * 16 + lrow;
                float bv = bias[n];
#pragma unroll
                for (int r = 0; r < 4; r++) {
                    int m = bm * 128 + wm * 64 + mi * 16 + lgrp * 4 + r;
                    float* o = (float*)outp;
                    o[(size_t)m * DMODEL + n] = acc[mi][ni][r] + bv + resid[(size_t)m * DMODEL + n];
                }
            }
        }
    }
}

// ---------------- Flash attention, causal ----------------
// q,k bf16 [head][seq][64]; vt bf16 [head][64][seq]; out bf16 [seq][1024].
// 4 waves x 16 q-rows = 64-row Q tile. Swapped QK^T (S^T), P in registers,
// PV via 16x16x16 MFMA. K/V^T double-buffered in LDS, XOR-swizzled, staged
// with global_load_lds(16B).
__global__ __launch_bounds__(256) void attn_kernel(const u16* __restrict__ q,
                                                   const u16* __restrict__ k,
                                                   const u16* __restrict__ vt,
                                                   u16* __restrict__ o) {
    __shared__ alignas(16) u16 Kl[2][64 * 64];
    __shared__ alignas(16) u16 Vl[2][64 * 64];
    int h = blockIdx.y;
    int qt = (int)(gridDim.x - 1) - blockIdx.x;      // long blocks first
    int q0 = qt * 64;
    int tid = threadIdx.x, wid = tid >> 6, lane = tid & 63;
    int t15 = lane & 15, g = lane >> 4;
    const u16* Qh  = q  + (size_t)h * SEQLEN * DKDIM;
    const u16* Kh  = k  + (size_t)h * SEQLEN * DKDIM;
    const u16* VtH = vt + (size_t)h * DKDIM * SEQLEN;

    int qrow = q0 + wid * 16 + t15;
    i32x4 qf0, qf1;
    {
        const u16* qp = Qh + (size_t)qrow * DKDIM + g * 8;
        qf0 = *reinterpret_cast<const i32x4*>(qp);
        qf1 = *reinterpret_cast<const i32x4*>(qp + 32);
    }
    f32x4 oacc[4] = {};
    float m_run = -1e30f, l_run = 0.f;

    int srow = wid * 16 + (lane >> 3);               // staging row base per wave-issue
    int sslot = lane & 7;

    // stage tile kt into buffer b: K and V^T, 64 rows x 128B each, pre-swizzled src
#define STAGE(b, kt_)                                                                   \
    {                                                                                   \
        int k0s = (kt_) * 64;                                                           \
        _Pragma("unroll")                                                               \
        for (int it = 0; it < 2; it++) {                                                \
            int u   = wid * 2 + it;                                                     \
            int row = u * 8 + (lane >> 3);                                              \
            int sl  = (sslot ^ (row & 7)) * 8;                                          \
            ASYNC_COPY16(Kh + (size_t)(k0s + row) * DKDIM + sl, &Kl[b][u * 512]);       \
            ASYNC_COPY16(VtH + (size_t)row * SEQLEN + k0s + sl, &Vl[b][u * 512]);       \
        }                                                                               \
    }

    STAGE(0, 0)
    __syncthreads();
    int buf = 0;
    for (int kt = 0; kt <= qt; kt++) {
        if (kt < qt) STAGE(buf ^ 1, kt + 1)
        int k0 = kt * 64;
        // ---- S^T = K . Q^T ----
        f32x4 sacc[4] = {};
#pragma unroll
        for (int kb = 0; kb < 4; kb++) {
            int j = kb * 16 + t15;
            i32x4 kf0 = *reinterpret_cast<const i32x4*>(&Kl[buf][j * 64 + ((g ^ (j & 7)) * 8)]);
            i32x4 kf1 = *reinterpret_cast<const i32x4*>(&Kl[buf][j * 64 + (((4 + g) ^ (j & 7)) * 8)]);
            mfma_bf16(sacc[kb], kf0, qf0);
            mfma_bf16(sacc[kb], kf1, qf1);
        }
        // ---- mask + online softmax (lane owns one q-row) ----
        float mx = m_run;
#pragma unroll
        for (int kb = 0; kb < 4; kb++)
#pragma unroll
            for (int r = 0; r < 4; r++) {
                int kvg = k0 + kb * 16 + g * 4 + r;
                float sv = sacc[kb][r] * 0.125f;
                sv = (kvg <= qrow) ? sv : -1e30f;
                sacc[kb][r] = sv;
                mx = fmaxf(mx, sv);
            }
        mx = fmaxf(mx, __shfl_xor(mx, 16));
        mx = fmaxf(mx, __shfl_xor(mx, 32));
        float fold = __expf(m_run - mx);
        m_run = mx;
        float psum = 0.f;
        u32 pk0, pk1, pk2, pk3, pk4, pk5, pk6, pk7;
#pragma unroll
        for (int kb = 0; kb < 4; kb++) {
            float p0 = __expf(sacc[kb][0] - mx);
            float p1 = __expf(sacc[kb][1] - mx);
            float p2 = __expf(sacc[kb][2] - mx);
            float p3 = __expf(sacc[kb][3] - mx);
            psum += (p0 + p1) + (p2 + p3);
            u32 lo = (u32)f2bf(p0) | ((u32)f2bf(p1) << 16);
            u32 hi = (u32)f2bf(p2) | ((u32)f2bf(p3) << 16);
            if (kb == 0) { pk0 = lo; pk1 = hi; }
            else if (kb == 1) { pk2 = lo; pk3 = hi; }
            else if (kb == 2) { pk4 = lo; pk5 = hi; }
            else { pk6 = lo; pk7 = hi; }
        }
        psum += __shfl_xor(psum, 16);
        psum += __shfl_xor(psum, 32);
        l_run = l_run * fold + psum;
#pragma unroll
        for (int nb = 0; nb < 4; nb++) oacc[nb] *= fold;
        // ---- O^T += V^T . P^T  (16x16x16, P already in B-layout) ----
#pragma unroll
        for (int nb = 0; nb < 4; nb++) {
            int d = nb * 16 + t15;
#pragma unroll
            for (int kb = 0; kb < 4; kb++) {
                i32x2 vf = *reinterpret_cast<const i32x2*>(
                    &Vl[buf][d * 64 + (((kb * 2 + (g >> 1)) ^ (d & 7)) * 8) + (g & 1) * 4]);
                i32x2 pf;
                if (kb == 0)      pf = i32x2{(int)pk0, (int)pk1};
                else if (kb == 1) pf = i32x2{(int)pk2, (int)pk3};
                else if (kb == 2) pf = i32x2{(int)pk4, (int)pk5};
                else              pf = i32x2{(int)pk6, (int)pk7};
                mfma16_bf16(oacc[nb], vf, pf);
            }
        }
        __syncthreads();
        buf ^= 1;
    }
    float inv_l = 1.0f / l_run;
#pragma unroll
    for (int nb = 0; nb < 4; nb++) {
        ushort4 w4;
        w4.x = f2bf(oacc[nb][0] * inv_l);
        w4.y = f2bf(oacc[nb][1] * inv_l);
        w4.z = f2bf(oacc[nb][2] * inv_l);
        w4.w = f2bf(oacc[nb][3] * inv_l);
        *reinterpret_cast<ushort4*>(&o[(size_t)qrow * DMODEL + h * DKDIM + nb * 16 + g * 4]) = w4;
    }
#undef STAGE
}

extern "C" void kernel_launch(void* const* d_in, const int* in_sizes, int n_in,
                              void* d_out, int out_size, void* d_ws, size_t ws_size,
                              hipStream_t stream) {
    const float* h     = (const float*)d_in[0];
    const float* gamma = (const float*)d_in[1];
    const float* beta  = (const float*)d_in[2];
    const float* Wq    = (const float*)d_in[3];
    const float* bq    = (const float*)d_in[4];
    const float* Wk    = (const float*)d_in[5];
    const float* bk    = (const float*)d_in[6];
    const float* Wv    = (const float*)d_in[7];
    const float* bv    = (const float*)d_in[8];
    const float* Wo    = (const float*)d_in[9];
    const float* bo    = (const float*)d_in[10];
    float* out = (float*)d_out;

    char* ws = (char*)d_ws;
    u16* hn   = (u16*)(ws);                        // 8 MiB; reused as attn output
    u16* wqT  = (u16*)(ws + (8ull  << 20));
    u16* wkT  = (u16*)(ws + (10ull << 20));
    u16* wvT  = (u16*)(ws + (12ull << 20));
    u16* woT  = (u16*)(ws + (14ull << 20));
    u16* qb   = (u16*)(ws + (16ull << 20));        // [16][4096][64]
    u16* kbuf = (u16*)(ws + (24ull << 20));        // [16][4096][64]
    u16* vtb  = (u16*)(ws + (32ull << 20));        // [16][64][4096]
    float* cosT = (float*)(ws + (40ull << 20));
    float* sinT = (float*)(ws + (40ull << 20) + (512ull << 10));
    u16* attn = hn;

    ln_kernel<<<SEQLEN, 256, 0, stream>>>(h, gamma, beta, hn);
    dim3 wgrid(32, 32);
    wconv_kernel<<<wgrid, 256, 0, stream>>>(Wq, wqT);
    wconv_kernel<<<wgrid, 256, 0, stream>>>(Wk, wkT);
    wconv_kernel<<<wgrid, 256, 0, stream>>>(Wv, wvT);
    wconv_kernel<<<wgrid, 256, 0, stream>>>(Wo, woT);
    rope_table_kernel<<<(SEQLEN * 32) / 256, 256, 0, stream>>>(cosT, sinT);
    dim3 ggrid(32, 8);
    gemm_kernel<0><<<ggrid, 256, 0, stream>>>(hn, wqT, bq, nullptr, cosT, sinT, qb);
    gemm_kernel<0><<<ggrid, 256, 0, stream>>>(hn, wkT, bk, nullptr, cosT, sinT, kbuf);
    gemm_kernel<2><<<ggrid, 256, 0, stream>>>(hn, wvT, bv, nullptr, cosT, sinT, vtb);
    dim3 agrid(SEQLEN / 64, NHEADS);
    attn_kernel<<<agrid, 256, 0, stream>>>(qb, kbuf, vtb, attn);
    gemm_kernel<1><<<ggrid, 256, 0, stream>>>(attn, woT, bo, h, cosT, sinT, out);
}

// Round 3
// 180.642 us; speedup vs baseline: 2.5158x; 1.5227x over previous
//
#include <hip/hip_runtime.h>
#include <stdint.h>

#define SEQLEN 4096
#define DMODEL 1024
#define NHEADS 16
#define DKDIM  64

typedef unsigned short u16;
typedef unsigned int   u32;
using f32x4 = __attribute__((ext_vector_type(4))) float;
using i32x4 = __attribute__((ext_vector_type(4))) int;
using i32x2 = __attribute__((ext_vector_type(2))) int;

__device__ __forceinline__ u16 f2bf(float f) {
    u32 x = __builtin_bit_cast(u32, f);
    u32 r = x + 0x7fffu + ((x >> 16) & 1u);   // RNE
    return (u16)(r >> 16);
}
__device__ __forceinline__ float exp2a(float x) {
    float r; asm("v_exp_f32 %0, %1" : "=v"(r) : "v"(x)); return r;
}
__device__ __forceinline__ u32 cvtpk(float lo, float hi) {
    u32 r; asm("v_cvt_pk_bf16_f32 %0, %1, %2" : "=v"(r) : "v"(lo), "v"(hi)); return r;
}

// 16x16x32: A lane holds A[lane&15][(lane>>4)*8+j]; B: B[(lane>>4)*8+j][lane&15];
// C/D: D[(lane>>4)*4+r][lane&15]
__device__ __forceinline__ void mfma_bf16(f32x4& d, i32x4 a, i32x4 b) {
    asm("v_mfma_f32_16x16x32_bf16 %0, %1, %2, %0" : "+v"(d) : "v"(a), "v"(b));
}
// 16x16x16: A lane holds A[lane&15][(lane>>4)*4+j]; B: B[(lane>>4)*4+j][lane&15]
__device__ __forceinline__ void mfma16_bf16(f32x4& d, i32x2 a, i32x2 b) {
    asm("v_mfma_f32_16x16x16_bf16 %0, %1, %2, %0" : "+v"(d) : "v"(a), "v"(b));
}

// async global->LDS, 16B per lane; LDS dest = wave-uniform base + lane*16
#define ASYNC_COPY16(gsrc, ldst) \
    __builtin_amdgcn_global_load_lds((const __attribute__((address_space(1))) void*)(gsrc), \
                                     (__attribute__((address_space(3))) void*)(ldst), 16, 0, 0)

// ---------------- LayerNorm: h fp32 [4096][1024] -> hn bf16 ----------------
__global__ __launch_bounds__(256) void ln_kernel(const float* __restrict__ h,
                                                 const float* __restrict__ gamma,
                                                 const float* __restrict__ beta,
                                                 u16* __restrict__ hn) {
    int row = blockIdx.x;
    int t = threadIdx.x;
    float4 v = reinterpret_cast<const float4*>(h + (size_t)row * DMODEL)[t];
    float s  = v.x + v.y + v.z + v.w;
    float s2 = v.x*v.x + v.y*v.y + v.z*v.z + v.w*v.w;
#pragma unroll
    for (int off = 1; off < 64; off <<= 1) {
        s  += __shfl_xor(s, off);
        s2 += __shfl_xor(s2, off);
    }
    __shared__ float red[8];
    int wid = t >> 6, lane = t & 63;
    if (lane == 0) { red[wid] = s; red[4 + wid] = s2; }
    __syncthreads();
    s  = red[0] + red[1] + red[2] + red[3];
    s2 = red[4] + red[5] + red[6] + red[7];
    float mu   = s * (1.0f / DMODEL);
    float rstd = rsqrtf(s2 * (1.0f / DMODEL) - mu * mu + 1e-5f);
    float4 g = reinterpret_cast<const float4*>(gamma)[t];
    float4 b = reinterpret_cast<const float4*>(beta)[t];
    ushort4 o;
    o.x = f2bf((v.x - mu) * rstd * g.x + b.x);
    o.y = f2bf((v.y - mu) * rstd * g.y + b.y);
    o.z = f2bf((v.z - mu) * rstd * g.z + b.z);
    o.w = f2bf((v.w - mu) * rstd * g.w + b.w);
    reinterpret_cast<ushort4*>(hn + (size_t)row * DMODEL)[t] = o;
}

// ---- Weight transpose+convert (all 4 weights): W fp32 [K][N] -> Wt bf16 [N][K] ----
__global__ __launch_bounds__(256) void wconv_kernel(const float* __restrict__ Wq,
                                                    const float* __restrict__ Wk,
                                                    const float* __restrict__ Wv,
                                                    const float* __restrict__ Wo,
                                                    u16* __restrict__ wqkvT,
                                                    u16* __restrict__ woT) {
    int z = blockIdx.z;
    const float* W = (z == 0) ? Wq : (z == 1) ? Wk : (z == 2) ? Wv : Wo;
    u16* Wt = (z < 3) ? wqkvT + (size_t)z * DMODEL * DMODEL : woT;
    __shared__ float tile[32][33];
    int bx = blockIdx.x * 32;   // n
    int by = blockIdx.y * 32;   // k
    int tx = threadIdx.x & 31, ty = threadIdx.x >> 5;
#pragma unroll
    for (int i = 0; i < 32; i += 8)
        tile[ty + i][tx] = W[(size_t)(by + ty + i) * DMODEL + bx + tx];
    __syncthreads();
#pragma unroll
    for (int i = 0; i < 32; i += 8)
        Wt[(size_t)(bx + ty + i) * DMODEL + by + tx] = f2bf(tile[tx][ty + i]);
}

// ---------------- RoPE cos/sin tables: [4096][32] fp32 each ----------------
__global__ void rope_table_kernel(float* __restrict__ cosT, float* __restrict__ sinT) {
    int idx = blockIdx.x * 256 + threadIdx.x;
    int s = idx >> 5, i = idx & 31;
    float theta = powf(10000.0f, -2.0f * (float)i / 64.0f);
    float ang = (float)s * theta;
    cosT[idx] = cosf(ang);
    sinT[idx] = sinf(ang);
}

// ---------------- GEMM: 128x128 tile, BK=64, global_load_lds double-buffer ----------------
// EPI=0: merged QKV (Bt rows 0..3071). seg=bn>>3: 0=Q (RoPE, *log2e/8 -> o0),
//        1=K (RoPE -> o1), 2=V (write V^T [head][64][seq] -> o2).
// EPI=1: +bias +residual, fp32 [seq][1024] -> ofp.
template <int EPI>
__global__ __launch_bounds__(256) void gemm_kernel(const u16* __restrict__ A,
                                                   const u16* __restrict__ Bt,
                                                   const float* __restrict__ b0,
                                                   const float* __restrict__ b1,
                                                   const float* __restrict__ b2,
                                                   const float* __restrict__ resid,
                                                   const float* __restrict__ cosT,
                                                   const float* __restrict__ sinT,
                                                   u16* __restrict__ o0,
                                                   u16* __restrict__ o1,
                                                   u16* __restrict__ o2,
                                                   float* __restrict__ ofp) {
    __shared__ alignas(16) u16 As[2][128 * 64];
    __shared__ alignas(16) u16 Bs[2][128 * 64];
    int bm = blockIdx.x, bn = blockIdx.y;
    int tid = threadIdx.x;
    int wid = tid >> 6, lane = tid & 63;
    int wm = wid >> 1, wn = wid & 1;
    int t15 = lane & 15, g = lane >> 4;
    const u16* Abase = A  + (size_t)bm * 128 * DMODEL;
    const u16* Bbase = Bt + (size_t)bn * 128 * DMODEL;
    int srow = tid >> 3;          // 0..31 within each 32-row issue chunk
    int sslot = tid & 7;
    f32x4 acc[4][4] = {};

    // LDS[row][slot] = global[row][slot ^ (row&7)]  (slots of 8 elems = 16B)
#define GSTAGE(b, ks)                                                                    \
    {                                                                                    \
        _Pragma("unroll")                                                                \
        for (int i = 0; i < 4; i++) {                                                    \
            int row = i * 32 + srow;                                                     \
            int col = ((sslot ^ (row & 7)) * 8) + (ks);                                  \
            ASYNC_COPY16(Abase + (size_t)row * DMODEL + col, &As[b][i * 2048 + wid * 512]); \
            ASYNC_COPY16(Bbase + (size_t)row * DMODEL + col, &Bs[b][i * 2048 + wid * 512]); \
        }                                                                                \
    }

    GSTAGE(0, 0)
    __syncthreads();
    int buf = 0;
    for (int ks = 0; ks < DMODEL; ks += 64) {
        if (ks < DMODEL - 64) GSTAGE(buf ^ 1, ks + 64)
#pragma unroll
        for (int kk = 0; kk < 2; kk++) {
            i32x4 af[4], bfr[4];
#pragma unroll
            for (int mi = 0; mi < 4; mi++) {
                int row = wm * 64 + mi * 16 + t15;
                int sl = (kk * 4 + g) ^ (row & 7);
                af[mi] = *reinterpret_cast<const i32x4*>(&As[buf][row * 64 + sl * 8]);
            }
#pragma unroll
            for (int ni = 0; ni < 4; ni++) {
                int row = wn * 64 + ni * 16 + t15;
                int sl = (kk * 4 + g) ^ (row & 7);
                bfr[ni] = *reinterpret_cast<const i32x4*>(&Bs[buf][row * 64 + sl * 8]);
            }
            __builtin_amdgcn_s_setprio(1);
#pragma unroll
            for (int mi = 0; mi < 4; mi++)
#pragma unroll
                for (int ni = 0; ni < 4; ni++)
                    mfma_bf16(acc[mi][ni], af[mi], bfr[ni]);
            __builtin_amdgcn_s_setprio(0);
        }
        __syncthreads();
        buf ^= 1;
    }
#undef GSTAGE

    if (EPI == 0) {
        int seg = bn >> 3;                 // 0=Q 1=K 2=V
        int bnl = bn & 7;
        const float* bias = (seg == 0) ? b0 : (seg == 1) ? b1 : b2;
        if (seg < 2) {
            u16* o = (seg == 0) ? o0 : o1;
            float qs = (seg == 0) ? 0.18033688f : 1.0f;   // log2(e)/8 for Q
#pragma unroll
            for (int mi = 0; mi < 4; mi++) {
#pragma unroll
                for (int nl = 0; nl < 2; nl++) {
                    int n10 = bnl * 128 + wn * 64 + nl * 16 + t15;  // d&63 in 0..31
                    int head = n10 >> 6;
                    int dA = n10 & 63, dB = dA + 32;
                    float bvA = bias[n10], bvB = bias[n10 + 32];
#pragma unroll
                    for (int r = 0; r < 4; r++) {
                        int m = bm * 128 + wm * 64 + mi * 16 + g * 4 + r;
                        float c  = cosT[m * 32 + dA];
                        float sn = sinT[m * 32 + dA];
                        float xA = acc[mi][nl][r] + bvA;
                        float xB = acc[mi][nl + 2][r] + bvB;
                        o[(size_t)(head * SEQLEN + m) * DKDIM + dA] = f2bf((xA * c - xB * sn) * qs);
                        o[(size_t)(head * SEQLEN + m) * DKDIM + dB] = f2bf((xB * c + xA * sn) * qs);
                    }
                }
            }
        } else {
#pragma unroll
            for (int mi = 0; mi < 4; mi++) {
#pragma unroll
                for (int ni = 0; ni < 4; ni++) {
                    int n10 = bnl * 128 + wn * 64 + ni * 16 + t15;
                    int head = n10 >> 6, dv = n10 & 63;
                    float bv = bias[n10];
                    int m = bm * 128 + wm * 64 + mi * 16 + g * 4;
                    ushort4 w4;
                    w4.x = f2bf(acc[mi][ni][0] + bv);
                    w4.y = f2bf(acc[mi][ni][1] + bv);
                    w4.z = f2bf(acc[mi][ni][2] + bv);
                    w4.w = f2bf(acc[mi][ni][3] + bv);
                    *reinterpret_cast<ushort4*>(&o2[(size_t)(head * DKDIM + dv) * SEQLEN + m]) = w4;
                }
            }
        }
    } else {
#pragma unroll
        for (int mi = 0; mi < 4; mi++) {
#pragma unroll
            for (int ni = 0; ni < 4; ni++) {
                int n = bn * 128 + wn * 64 + ni * 16 + t15;
                float bv = b0[n];
#pragma unroll
                for (int r = 0; r < 4; r++) {
                    int m = bm * 128 + wm * 64 + mi * 16 + g * 4 + r;
                    ofp[(size_t)m * DMODEL + n] = acc[mi][ni][r] + bv + resid[(size_t)m * DMODEL + n];
                }
            }
        }
    }
}

// ---------------- Flash attention, causal, exp2-domain, defer-max ----------------
// q (pre-scaled by log2e/8), k bf16 [head][seq][64]; vt bf16 [head][64][seq];
// out bf16 [seq][1024]. 4 waves x 16 q-rows; swapped QK^T; P in registers.
__global__ __launch_bounds__(256) void attn_kernel(const u16* __restrict__ q,
                                                   const u16* __restrict__ k,
                                                   const u16* __restrict__ vt,
                                                   u16* __restrict__ o) {
    __shared__ alignas(16) u16 Kl[2][64 * 64];
    __shared__ alignas(16) u16 Vl[2][64 * 64];
    int h = blockIdx.y;
    int qt = (int)(gridDim.x - 1) - blockIdx.x;      // long blocks first
    int q0 = qt * 64;
    int tid = threadIdx.x, wid = tid >> 6, lane = tid & 63;
    int t15 = lane & 15, g = lane >> 4;
    const u16* Qh  = q  + (size_t)h * SEQLEN * DKDIM;
    const u16* Kh  = k  + (size_t)h * SEQLEN * DKDIM;
    const u16* VtH = vt + (size_t)h * DKDIM * SEQLEN;

    int qrow = q0 + wid * 16 + t15;
    i32x4 qf0, qf1;
    {
        const u16* qp = Qh + (size_t)qrow * DKDIM + g * 8;
        qf0 = *reinterpret_cast<const i32x4*>(qp);
        qf1 = *reinterpret_cast<const i32x4*>(qp + 32);
    }
    f32x4 oacc[4] = {};
    float m_run = -1e30f, l_part = 0.f;
    int sslot = lane & 7;

#define STAGE(b, kt_)                                                                   \
    {                                                                                   \
        int k0s = (kt_) * 64;                                                           \
        _Pragma("unroll")                                                               \
        for (int it = 0; it < 2; it++) {                                                \
            int u   = wid * 2 + it;                                                     \
            int row = u * 8 + (lane >> 3);                                              \
            int sl  = (sslot ^ (row & 7)) * 8;                                          \
            ASYNC_COPY16(Kh + (size_t)(k0s + row) * DKDIM + sl, &Kl[b][u * 512]);       \
            ASYNC_COPY16(VtH + (size_t)row * SEQLEN + k0s + sl, &Vl[b][u * 512]);       \
        }                                                                               \
    }

    STAGE(0, 0)
    __syncthreads();
    int buf = 0;
    for (int kt = 0; kt <= qt; kt++) {
        if (kt < qt) STAGE(buf ^ 1, kt + 1)
        int k0 = kt * 64;
        // ---- S^T = K . Q^T  (already in exp2 domain via Q prescale) ----
        f32x4 sacc[4] = {};
        __builtin_amdgcn_s_setprio(1);
#pragma unroll
        for (int kb = 0; kb < 4; kb++) {
            int j = kb * 16 + t15;
            i32x4 kf0 = *reinterpret_cast<const i32x4*>(&Kl[buf][j * 64 + ((g ^ (j & 7)) * 8)]);
            i32x4 kf1 = *reinterpret_cast<const i32x4*>(&Kl[buf][j * 64 + (((4 + g) ^ (j & 7)) * 8)]);
            mfma_bf16(sacc[kb], kf0, qf0);
            mfma_bf16(sacc[kb], kf1, qf1);
        }
        __builtin_amdgcn_s_setprio(0);
        // ---- causal mask: only the diagonal tile ----
        if (kt == qt) {
#pragma unroll
            for (int kb = 0; kb < 4; kb++)
#pragma unroll
                for (int r = 0; r < 4; r++) {
                    int kvg = k0 + kb * 16 + g * 4 + r;
                    if (kvg > qrow) sacc[kb][r] = -1e30f;
                }
        }
        // ---- per-lane tile max (tree) + defer-max ----
        float a0 = fmaxf(fmaxf(sacc[0][0], sacc[0][1]), fmaxf(sacc[0][2], sacc[0][3]));
        float a1 = fmaxf(fmaxf(sacc[1][0], sacc[1][1]), fmaxf(sacc[1][2], sacc[1][3]));
        float a2 = fmaxf(fmaxf(sacc[2][0], sacc[2][1]), fmaxf(sacc[2][2], sacc[2][3]));
        float a3 = fmaxf(fmaxf(sacc[3][0], sacc[3][1]), fmaxf(sacc[3][2], sacc[3][3]));
        float mx = fmaxf(fmaxf(a0, a1), fmaxf(a2, a3));
        if (!__all(mx <= m_run + 8.0f)) {
            float mrow = fmaxf(mx, __shfl_xor(mx, 16));
            mrow = fmaxf(mrow, __shfl_xor(mrow, 32));
            float mnew = fmaxf(m_run, mrow);
            float fold = exp2a(m_run - mnew);
            m_run = mnew;
            l_part *= fold;
            oacc[0] *= fold; oacc[1] *= fold; oacc[2] *= fold; oacc[3] *= fold;
        }
        // ---- p = exp2(s - m), pack bf16 ----
        float ps = 0.f;
        u32 pw[8];
#pragma unroll
        for (int kb = 0; kb < 4; kb++) {
            float p0 = exp2a(sacc[kb][0] - m_run);
            float p1 = exp2a(sacc[kb][1] - m_run);
            float p2 = exp2a(sacc[kb][2] - m_run);
            float p3 = exp2a(sacc[kb][3] - m_run);
            ps += (p0 + p1) + (p2 + p3);
            pw[kb * 2]     = cvtpk(p0, p1);
            pw[kb * 2 + 1] = cvtpk(p2, p3);
        }
        l_part += ps;
        // ---- O^T += V^T . P^T  (16x16x16, P in B-layout) ----
        __builtin_amdgcn_s_setprio(1);
#pragma unroll
        for (int nb = 0; nb < 4; nb++) {
            int d = nb * 16 + t15;
#pragma unroll
            for (int kb = 0; kb < 4; kb++) {
                i32x2 vf = *reinterpret_cast<const i32x2*>(
                    &Vl[buf][d * 64 + (((kb * 2 + (g >> 1)) ^ (d & 7)) * 8) + (g & 1) * 4]);
                i32x2 pf = i32x2{(int)pw[kb * 2], (int)pw[kb * 2 + 1]};
                mfma16_bf16(oacc[nb], vf, pf);
            }
        }
        __builtin_amdgcn_s_setprio(0);
        __syncthreads();
        buf ^= 1;
    }
#undef STAGE
    float l = l_part;
    l += __shfl_xor(l, 16);
    l += __shfl_xor(l, 32);
    float inv_l = 1.0f / l;
#pragma unroll
    for (int nb = 0; nb < 4; nb++) {
        ushort4 w4;
        w4.x = f2bf(oacc[nb][0] * inv_l);
        w4.y = f2bf(oacc[nb][1] * inv_l);
        w4.z = f2bf(oacc[nb][2] * inv_l);
        w4.w = f2bf(oacc[nb][3] * inv_l);
        *reinterpret_cast<ushort4*>(&o[(size_t)qrow * DMODEL + h * DKDIM + nb * 16 + g * 4]) = w4;
    }
}

extern "C" void kernel_launch(void* const* d_in, const int* in_sizes, int n_in,
                              void* d_out, int out_size, void* d_ws, size_t ws_size,
                              hipStream_t stream) {
    const float* h     = (const float*)d_in[0];
    const float* gamma = (const float*)d_in[1];
    const float* beta  = (const float*)d_in[2];
    const float* Wq    = (const float*)d_in[3];
    const float* bq    = (const float*)d_in[4];
    const float* Wk    = (const float*)d_in[5];
    const float* bk    = (const float*)d_in[6];
    const float* Wv    = (const float*)d_in[7];
    const float* bv    = (const float*)d_in[8];
    const float* Wo    = (const float*)d_in[9];
    const float* bo    = (const float*)d_in[10];
    float* out = (float*)d_out;

    char* ws = (char*)d_ws;
    u16* hn     = (u16*)(ws);                        // 8 MiB; reused as attn output
    u16* wqkvT  = (u16*)(ws + (8ull  << 20));        // 6 MiB [3072][1024]
    u16* woT    = (u16*)(ws + (14ull << 20));        // 2 MiB
    u16* qb     = (u16*)(ws + (16ull << 20));        // [16][4096][64]
    u16* kbuf   = (u16*)(ws + (24ull << 20));        // [16][4096][64]
    u16* vtb    = (u16*)(ws + (32ull << 20));        // [16][64][4096]
    float* cosT = (float*)(ws + (40ull << 20));
    float* sinT = (float*)(ws + (40ull << 20) + (512ull << 10));
    u16* attn = hn;

    ln_kernel<<<SEQLEN, 256, 0, stream>>>(h, gamma, beta, hn);
    wconv_kernel<<<dim3(32, 32, 4), 256, 0, stream>>>(Wq, Wk, Wv, Wo, wqkvT, woT);
    rope_table_kernel<<<(SEQLEN * 32) / 256, 256, 0, stream>>>(cosT, sinT);
    gemm_kernel<0><<<dim3(32, 24), 256, 0, stream>>>(hn, wqkvT, bq, bk, bv, nullptr,
                                                     cosT, sinT, qb, kbuf, vtb, nullptr);
    dim3 agrid(SEQLEN / 64, NHEADS);
    attn_kernel<<<agrid, 256, 0, stream>>>(qb, kbuf, vtb, attn);
    gemm_kernel<1><<<dim3(32, 8), 256, 0, stream>>>(attn, woT, bo, nullptr, nullptr, h,
                                                    nullptr, nullptr, nullptr, nullptr, nullptr, out);
}

// Round 4
// 159.300 us; speedup vs baseline: 2.8528x; 1.1340x over previous
//
#include <hip/hip_runtime.h>
#include <stdint.h>

#define SEQLEN 4096
#define DMODEL 1024
#define NHEADS 16
#define DKDIM  64

typedef unsigned short u16;
typedef unsigned int   u32;
using f32x4 = __attribute__((ext_vector_type(4))) float;
using i32x4 = __attribute__((ext_vector_type(4))) int;
using i32x2 = __attribute__((ext_vector_type(2))) int;

__device__ __forceinline__ u16 f2bf(float f) {
    u32 x = __builtin_bit_cast(u32, f);
    u32 r = x + 0x7fffu + ((x >> 16) & 1u);   // RNE
    return (u16)(r >> 16);
}
__device__ __forceinline__ float exp2a(float x) {
    float r; asm("v_exp_f32 %0, %1" : "=v"(r) : "v"(x)); return r;
}
__device__ __forceinline__ u32 cvtpk(float lo, float hi) {
    u32 r; asm("v_cvt_pk_bf16_f32 %0, %1, %2" : "=v"(r) : "v"(lo), "v"(hi)); return r;
}

// 16x16x32: A lane holds A[lane&15][(lane>>4)*8+j]; B: B[(lane>>4)*8+j][lane&15];
// C/D: D[(lane>>4)*4+r][lane&15]
__device__ __forceinline__ void mfma_bf16(f32x4& d, i32x4 a, i32x4 b) {
    asm("v_mfma_f32_16x16x32_bf16 %0, %1, %2, %0" : "+v"(d) : "v"(a), "v"(b));
}
// 16x16x16: A lane holds A[lane&15][(lane>>4)*4+j]; B: B[(lane>>4)*4+j][lane&15]
__device__ __forceinline__ void mfma16_bf16(f32x4& d, i32x2 a, i32x2 b) {
    asm("v_mfma_f32_16x16x16_bf16 %0, %1, %2, %0" : "+v"(d) : "v"(a), "v"(b));
}

// async global->LDS, 16B per lane; LDS dest = wave-uniform base + lane*16
#define ASYNC_COPY16(gsrc, ldst) \
    __builtin_amdgcn_global_load_lds((const __attribute__((address_space(1))) void*)(gsrc), \
                                     (__attribute__((address_space(3))) void*)(ldst), 16, 0, 0)

// ---------------- LayerNorm: h fp32 [4096][1024] -> hn bf16 ----------------
__global__ __launch_bounds__(256) void ln_kernel(const float* __restrict__ h,
                                                 const float* __restrict__ gamma,
                                                 const float* __restrict__ beta,
                                                 u16* __restrict__ hn) {
    int row = blockIdx.x;
    int t = threadIdx.x;
    float4 v = reinterpret_cast<const float4*>(h + (size_t)row * DMODEL)[t];
    float s  = v.x + v.y + v.z + v.w;
    float s2 = v.x*v.x + v.y*v.y + v.z*v.z + v.w*v.w;
#pragma unroll
    for (int off = 1; off < 64; off <<= 1) {
        s  += __shfl_xor(s, off);
        s2 += __shfl_xor(s2, off);
    }
    __shared__ float red[8];
    int wid = t >> 6, lane = t & 63;
    if (lane == 0) { red[wid] = s; red[4 + wid] = s2; }
    __syncthreads();
    s  = red[0] + red[1] + red[2] + red[3];
    s2 = red[4] + red[5] + red[6] + red[7];
    float mu   = s * (1.0f / DMODEL);
    float rstd = rsqrtf(s2 * (1.0f / DMODEL) - mu * mu + 1e-5f);
    float4 g = reinterpret_cast<const float4*>(gamma)[t];
    float4 b = reinterpret_cast<const float4*>(beta)[t];
    ushort4 o;
    o.x = f2bf((v.x - mu) * rstd * g.x + b.x);
    o.y = f2bf((v.y - mu) * rstd * g.y + b.y);
    o.z = f2bf((v.z - mu) * rstd * g.z + b.z);
    o.w = f2bf((v.w - mu) * rstd * g.w + b.w);
    reinterpret_cast<ushort4*>(hn + (size_t)row * DMODEL)[t] = o;
}

// ---- Weight transpose+convert (all 4 weights): W fp32 [K][N] -> Wt bf16 [N][K] ----
__global__ __launch_bounds__(256) void wconv_kernel(const float* __restrict__ Wq,
                                                    const float* __restrict__ Wk,
                                                    const float* __restrict__ Wv,
                                                    const float* __restrict__ Wo,
                                                    u16* __restrict__ wqkvT,
                                                    u16* __restrict__ woT) {
    int z = blockIdx.z;
    const float* W = (z == 0) ? Wq : (z == 1) ? Wk : (z == 2) ? Wv : Wo;
    u16* Wt = (z < 3) ? wqkvT + (size_t)z * DMODEL * DMODEL : woT;
    __shared__ float tile[32][33];
    int bx = blockIdx.x * 32;   // n
    int by = blockIdx.y * 32;   // k
    int tx = threadIdx.x & 31, ty = threadIdx.x >> 5;
#pragma unroll
    for (int i = 0; i < 32; i += 8)
        tile[ty + i][tx] = W[(size_t)(by + ty + i) * DMODEL + bx + tx];
    __syncthreads();
#pragma unroll
    for (int i = 0; i < 32; i += 8)
        Wt[(size_t)(bx + ty + i) * DMODEL + by + tx] = f2bf(tile[tx][ty + i]);
}

// ---------------- RoPE cos/sin tables: [4096][32] fp32 each ----------------
__global__ void rope_table_kernel(float* __restrict__ cosT, float* __restrict__ sinT) {
    int idx = blockIdx.x * 256 + threadIdx.x;
    int s = idx >> 5, i = idx & 31;
    float theta = powf(10000.0f, -2.0f * (float)i / 64.0f);
    float ang = (float)s * theta;
    cosT[idx] = cosf(ang);
    sinT[idx] = sinf(ang);
}

// ---------------- GEMM: 128x128 tile, BK=64, global_load_lds double-buffer ----------------
// EPI=0: merged QKV (Bt rows 0..3071). seg=bn>>3: 0=Q (RoPE, *log2e/8 -> o0),
//        1=K (RoPE -> o1), 2=V (write V^T [head][64][seq] -> o2).
// EPI=1: +bias +residual, fp32 [seq][1024] -> ofp.
template <int EPI>
__global__ __launch_bounds__(256) void gemm_kernel(const u16* __restrict__ A,
                                                   const u16* __restrict__ Bt,
                                                   const float* __restrict__ b0,
                                                   const float* __restrict__ b1,
                                                   const float* __restrict__ b2,
                                                   const float* __restrict__ resid,
                                                   const float* __restrict__ cosT,
                                                   const float* __restrict__ sinT,
                                                   u16* __restrict__ o0,
                                                   u16* __restrict__ o1,
                                                   u16* __restrict__ o2,
                                                   float* __restrict__ ofp) {
    __shared__ alignas(16) u16 As[2][128 * 64];
    __shared__ alignas(16) u16 Bs[2][128 * 64];
    int bm = blockIdx.x, bn = blockIdx.y;
    int tid = threadIdx.x;
    int wid = tid >> 6, lane = tid & 63;
    int wm = wid >> 1, wn = wid & 1;
    int t15 = lane & 15, g = lane >> 4;
    const u16* Abase = A  + (size_t)bm * 128 * DMODEL;
    const u16* Bbase = Bt + (size_t)bn * 128 * DMODEL;
    int srow = tid >> 3;          // 0..31 within each 32-row issue chunk
    int sslot = tid & 7;
    f32x4 acc[4][4] = {};

    // LDS[row][slot] = global[row][slot ^ (row&7)]  (slots of 8 elems = 16B)
#define GSTAGE(b, ks)                                                                    \
    {                                                                                    \
        _Pragma("unroll")                                                                \
        for (int i = 0; i < 4; i++) {                                                    \
            int row = i * 32 + srow;                                                     \
            int col = ((sslot ^ (row & 7)) * 8) + (ks);                                  \
            ASYNC_COPY16(Abase + (size_t)row * DMODEL + col, &As[b][i * 2048 + wid * 512]); \
            ASYNC_COPY16(Bbase + (size_t)row * DMODEL + col, &Bs[b][i * 2048 + wid * 512]); \
        }                                                                                \
    }

    GSTAGE(0, 0)
    __syncthreads();
    int buf = 0;
    for (int ks = 0; ks < DMODEL; ks += 64) {
        if (ks < DMODEL - 64) GSTAGE(buf ^ 1, ks + 64)
#pragma unroll
        for (int kk = 0; kk < 2; kk++) {
            i32x4 af[4], bfr[4];
#pragma unroll
            for (int mi = 0; mi < 4; mi++) {
                int row = wm * 64 + mi * 16 + t15;
                int sl = (kk * 4 + g) ^ (row & 7);
                af[mi] = *reinterpret_cast<const i32x4*>(&As[buf][row * 64 + sl * 8]);
            }
#pragma unroll
            for (int ni = 0; ni < 4; ni++) {
                int row = wn * 64 + ni * 16 + t15;
                int sl = (kk * 4 + g) ^ (row & 7);
                bfr[ni] = *reinterpret_cast<const i32x4*>(&Bs[buf][row * 64 + sl * 8]);
            }
            __builtin_amdgcn_s_setprio(1);
#pragma unroll
            for (int mi = 0; mi < 4; mi++)
#pragma unroll
                for (int ni = 0; ni < 4; ni++)
                    mfma_bf16(acc[mi][ni], af[mi], bfr[ni]);
            __builtin_amdgcn_s_setprio(0);
        }
        __syncthreads();
        buf ^= 1;
    }
#undef GSTAGE

    if (EPI == 0) {
        int seg = bn >> 3;                 // 0=Q 1=K 2=V
        int bnl = bn & 7;
        const float* bias = (seg == 0) ? b0 : (seg == 1) ? b1 : b2;
        if (seg < 2) {
            u16* o = (seg == 0) ? o0 : o1;
            float qs = (seg == 0) ? 0.18033688f : 1.0f;   // log2(e)/8 for Q
#pragma unroll
            for (int mi = 0; mi < 4; mi++) {
#pragma unroll
                for (int nl = 0; nl < 2; nl++) {
                    int n10 = bnl * 128 + wn * 64 + nl * 16 + t15;  // d&63 in 0..31
                    int head = n10 >> 6;
                    int dA = n10 & 63, dB = dA + 32;
                    float bvA = bias[n10], bvB = bias[n10 + 32];
#pragma unroll
                    for (int r = 0; r < 4; r++) {
                        int m = bm * 128 + wm * 64 + mi * 16 + g * 4 + r;
                        float c  = cosT[m * 32 + dA];
                        float sn = sinT[m * 32 + dA];
                        float xA = acc[mi][nl][r] + bvA;
                        float xB = acc[mi][nl + 2][r] + bvB;
                        o[(size_t)(head * SEQLEN + m) * DKDIM + dA] = f2bf((xA * c - xB * sn) * qs);
                        o[(size_t)(head * SEQLEN + m) * DKDIM + dB] = f2bf((xB * c + xA * sn) * qs);
                    }
                }
            }
        } else {
#pragma unroll
            for (int mi = 0; mi < 4; mi++) {
#pragma unroll
                for (int ni = 0; ni < 4; ni++) {
                    int n10 = bnl * 128 + wn * 64 + ni * 16 + t15;
                    int head = n10 >> 6, dv = n10 & 63;
                    float bv = bias[n10];
                    int m = bm * 128 + wm * 64 + mi * 16 + g * 4;
                    ushort4 w4;
                    w4.x = f2bf(acc[mi][ni][0] + bv);
                    w4.y = f2bf(acc[mi][ni][1] + bv);
                    w4.z = f2bf(acc[mi][ni][2] + bv);
                    w4.w = f2bf(acc[mi][ni][3] + bv);
                    *reinterpret_cast<ushort4*>(&o2[(size_t)(head * DKDIM + dv) * SEQLEN + m]) = w4;
                }
            }
        }
    } else {
#pragma unroll
        for (int mi = 0; mi < 4; mi++) {
#pragma unroll
            for (int ni = 0; ni < 4; ni++) {
                int n = bn * 128 + wn * 64 + ni * 16 + t15;
                float bv = b0[n];
#pragma unroll
                for (int r = 0; r < 4; r++) {
                    int m = bm * 128 + wm * 64 + mi * 16 + g * 4 + r;
                    ofp[(size_t)m * DMODEL + n] = acc[mi][ni][r] + bv + resid[(size_t)m * DMODEL + n];
                }
            }
        }
    }
}

// ---------------- Flash attention, causal, exp2-domain, defer-max ----------------
// q (pre-scaled by log2e/8), k bf16 [head][seq][64]; vt bf16 [head][64][seq];
// out bf16 [seq][1024]. 4 waves x 16 q-rows; swapped QK^T; P in registers.
// Triangle pairing: block p handles q-tiles {63-p, p} -> exactly 65 kv-tiles
// per block, all 512 blocks identical (removes CU load imbalance).
__global__ __launch_bounds__(256) void attn_kernel(const u16* __restrict__ q,
                                                   const u16* __restrict__ k,
                                                   const u16* __restrict__ vt,
                                                   u16* __restrict__ o) {
    __shared__ alignas(16) u16 Kl[2][64 * 64];
    __shared__ alignas(16) u16 Vl[2][64 * 64];
    int h = blockIdx.y;
    int p = blockIdx.x;                              // 0..31
    int tid = threadIdx.x, wid = tid >> 6, lane = tid & 63;
    int t15 = lane & 15, g = lane >> 4;
    const u16* Qh  = q  + (size_t)h * SEQLEN * DKDIM;
    const u16* Kh  = k  + (size_t)h * SEQLEN * DKDIM;
    const u16* VtH = vt + (size_t)h * DKDIM * SEQLEN;
    int sslot = lane & 7;

#define STAGE(b, kt_)                                                                   \
    {                                                                                   \
        int k0s = (kt_) * 64;                                                           \
        _Pragma("unroll")                                                               \
        for (int it = 0; it < 2; it++) {                                                \
            int u   = wid * 2 + it;                                                     \
            int row = u * 8 + (lane >> 3);                                              \
            int sl  = (sslot ^ (row & 7)) * 8;                                          \
            ASYNC_COPY16(Kh + (size_t)(k0s + row) * DKDIM + sl, &Kl[b][u * 512]);       \
            ASYNC_COPY16(VtH + (size_t)row * SEQLEN + k0s + sl, &Vl[b][u * 512]);       \
        }                                                                               \
    }

    for (int pass = 0; pass < 2; pass++) {
        int qt = pass ? p : (63 - p);
        int q0 = qt * 64;
        int qrow = q0 + wid * 16 + t15;
        i32x4 qf0, qf1;
        {
            const u16* qp = Qh + (size_t)qrow * DKDIM + g * 8;
            qf0 = *reinterpret_cast<const i32x4*>(qp);
            qf1 = *reinterpret_cast<const i32x4*>(qp + 32);
        }
        f32x4 oacc[4] = {};
        float m_run = -1e30f, l_part = 0.f;

        STAGE(0, 0)
        __syncthreads();
        int buf = 0;
        for (int kt = 0; kt <= qt; kt++) {
            if (kt < qt) STAGE(buf ^ 1, kt + 1)
            int k0 = kt * 64;
            // ---- S^T = K . Q^T  (already in exp2 domain via Q prescale) ----
            f32x4 sacc[4] = {};
            __builtin_amdgcn_s_setprio(1);
#pragma unroll
            for (int kb = 0; kb < 4; kb++) {
                int j = kb * 16 + t15;
                i32x4 kf0 = *reinterpret_cast<const i32x4*>(&Kl[buf][j * 64 + ((g ^ (j & 7)) * 8)]);
                i32x4 kf1 = *reinterpret_cast<const i32x4*>(&Kl[buf][j * 64 + (((4 + g) ^ (j & 7)) * 8)]);
                mfma_bf16(sacc[kb], kf0, qf0);
                mfma_bf16(sacc[kb], kf1, qf1);
            }
            __builtin_amdgcn_s_setprio(0);
            // ---- causal mask: only the diagonal tile ----
            if (kt == qt) {
#pragma unroll
                for (int kb = 0; kb < 4; kb++)
#pragma unroll
                    for (int r = 0; r < 4; r++) {
                        int kvg = k0 + kb * 16 + g * 4 + r;
                        if (kvg > qrow) sacc[kb][r] = -1e30f;
                    }
            }
            // ---- per-lane tile max (tree) + defer-max ----
            float a0 = fmaxf(fmaxf(sacc[0][0], sacc[0][1]), fmaxf(sacc[0][2], sacc[0][3]));
            float a1 = fmaxf(fmaxf(sacc[1][0], sacc[1][1]), fmaxf(sacc[1][2], sacc[1][3]));
            float a2 = fmaxf(fmaxf(sacc[2][0], sacc[2][1]), fmaxf(sacc[2][2], sacc[2][3]));
            float a3 = fmaxf(fmaxf(sacc[3][0], sacc[3][1]), fmaxf(sacc[3][2], sacc[3][3]));
            float mx = fmaxf(fmaxf(a0, a1), fmaxf(a2, a3));
            if (!__all(mx <= m_run + 8.0f)) {
                float mrow = fmaxf(mx, __shfl_xor(mx, 16));
                mrow = fmaxf(mrow, __shfl_xor(mrow, 32));
                float mnew = fmaxf(m_run, mrow);
                float fold = exp2a(m_run - mnew);
                m_run = mnew;
                l_part *= fold;
                oacc[0] *= fold; oacc[1] *= fold; oacc[2] *= fold; oacc[3] *= fold;
            }
            // ---- p = exp2(s - m), pack bf16 ----
            float ps = 0.f;
            u32 pw[8];
#pragma unroll
            for (int kb = 0; kb < 4; kb++) {
                float p0 = exp2a(sacc[kb][0] - m_run);
                float p1 = exp2a(sacc[kb][1] - m_run);
                float p2 = exp2a(sacc[kb][2] - m_run);
                float p3 = exp2a(sacc[kb][3] - m_run);
                ps += (p0 + p1) + (p2 + p3);
                pw[kb * 2]     = cvtpk(p0, p1);
                pw[kb * 2 + 1] = cvtpk(p2, p3);
            }
            l_part += ps;
            // ---- O^T += V^T . P^T  (16x16x16, P in B-layout) ----
            __builtin_amdgcn_s_setprio(1);
#pragma unroll
            for (int nb = 0; nb < 4; nb++) {
                int d = nb * 16 + t15;
#pragma unroll
                for (int kb = 0; kb < 4; kb++) {
                    i32x2 vf = *reinterpret_cast<const i32x2*>(
                        &Vl[buf][d * 64 + (((kb * 2 + (g >> 1)) ^ (d & 7)) * 8) + (g & 1) * 4]);
                    i32x2 pf = i32x2{(int)pw[kb * 2], (int)pw[kb * 2 + 1]};
                    mfma16_bf16(oacc[nb], vf, pf);
                }
            }
            __builtin_amdgcn_s_setprio(0);
            __syncthreads();
            buf ^= 1;
        }
        float l = l_part;
        l += __shfl_xor(l, 16);
        l += __shfl_xor(l, 32);
        float inv_l = 1.0f / l;
#pragma unroll
        for (int nb = 0; nb < 4; nb++) {
            ushort4 w4;
            w4.x = f2bf(oacc[nb][0] * inv_l);
            w4.y = f2bf(oacc[nb][1] * inv_l);
            w4.z = f2bf(oacc[nb][2] * inv_l);
            w4.w = f2bf(oacc[nb][3] * inv_l);
            *reinterpret_cast<ushort4*>(&o[(size_t)qrow * DMODEL + h * DKDIM + nb * 16 + g * 4]) = w4;
        }
    }
#undef STAGE
}

extern "C" void kernel_launch(void* const* d_in, const int* in_sizes, int n_in,
                              void* d_out, int out_size, void* d_ws, size_t ws_size,
                              hipStream_t stream) {
    const float* h     = (const float*)d_in[0];
    const float* gamma = (const float*)d_in[1];
    const float* beta  = (const float*)d_in[2];
    const float* Wq    = (const float*)d_in[3];
    const float* bq    = (const float*)d_in[4];
    const float* Wk    = (const float*)d_in[5];
    const float* bk    = (const float*)d_in[6];
    const float* Wv    = (const float*)d_in[7];
    const float* bv    = (const float*)d_in[8];
    const float* Wo    = (const float*)d_in[9];
    const float* bo    = (const float*)d_in[10];
    float* out = (float*)d_out;

    char* ws = (char*)d_ws;
    u16* hn     = (u16*)(ws);                        // 8 MiB; reused as attn output
    u16* wqkvT  = (u16*)(ws + (8ull  << 20));        // 6 MiB [3072][1024]
    u16* woT    = (u16*)(ws + (14ull << 20));        // 2 MiB
    u16* qb     = (u16*)(ws + (16ull << 20));        // [16][4096][64]
    u16* kbuf   = (u16*)(ws + (24ull << 20));        // [16][4096][64]
    u16* vtb    = (u16*)(ws + (32ull << 20));        // [16][64][4096]
    float* cosT = (float*)(ws + (40ull << 20));
    float* sinT = (float*)(ws + (40ull << 20) + (512ull << 10));
    u16* attn = hn;

    ln_kernel<<<SEQLEN, 256, 0, stream>>>(h, gamma, beta, hn);
    wconv_kernel<<<dim3(32, 32, 4), 256, 0, stream>>>(Wq, Wk, Wv, Wo, wqkvT, woT);
    rope_table_kernel<<<(SEQLEN * 32) / 256, 256, 0, stream>>>(cosT, sinT);
    gemm_kernel<0><<<dim3(32, 24), 256, 0, stream>>>(hn, wqkvT, bq, bk, bv, nullptr,
                                                     cosT, sinT, qb, kbuf, vtb, nullptr);
    dim3 agrid(32, NHEADS);
    attn_kernel<<<agrid, 256, 0, stream>>>(qb, kbuf, vtb, attn);
    gemm_kernel<1><<<dim3(32, 8), 256, 0, stream>>>(attn, woT, bo, nullptr, nullptr, h,
                                                    nullptr, nullptr, nullptr, nullptr, nullptr, out);
}